// Round 8
// baseline (164.503 us; speedup 1.0000x reference)
//
#include <hip/hip_runtime.h>
#include <hip/hip_bf16.h>

#define BATCH 16
#define HW 50176          // 224*224
#define HID 256
#define K 64

// output layout (floats): transformed [0, 2408448) | m [2408448, 53788672) | palette [53788672, +3072)
#define OUT_T_OFF 0
#define OUT_M_OFF 2408448
#define OUT_P_OFF 53788672

// workspace layout (floats): den [0,1024) | num [1024,4096) | w1p float4 [4096,5120) | w2b bf16 @ float-offset 5120 (32KB)
#define WS_DEN 0
#define WS_NUM 1024
#define WS_W1P 4096
#define WS_W2B 5120

typedef short bf16x8 __attribute__((ext_vector_type(8)));
typedef float f32x4  __attribute__((ext_vector_type(4)));

static __device__ __forceinline__ short f2bf(float x) {
    union { __hip_bfloat16 h; short s; } u;
    u.h = __float2bfloat16(x);
    return u.s;
}

// Prep (8 blocks): block 0 zeroes den/num and packs W1+b1; all blocks convert W2 slice to bf16.
__global__ __launch_bounds__(256) void colorcnn_prep(
    const float* __restrict__ W1, const float* __restrict__ b1,
    const float* __restrict__ W2, float* __restrict__ wsf,
    float4* __restrict__ w1p, ushort* __restrict__ w2b)
{
    const int t = threadIdx.x;
    if (blockIdx.x == 0) {
#pragma unroll
        for (int q = 0; q < 16; ++q) wsf[q * 256 + t] = 0.f;   // den[1024] + num[3072]
        w1p[t] = make_float4(W1[3 * t], W1[3 * t + 1], W1[3 * t + 2], b1[t]);
    }
#pragma unroll
    for (int q = 0; q < 8; ++q) {
        const int i = (blockIdx.x * 8 + q) * 256 + t;
        w2b[i] = (ushort)f2bf(W2[i]);
    }
}

// Shared MLP+softmax core: stages weights in LDS, computes m for 256 px (4 waves x 64 px)
// into acc[4][4] (C layout: col(n)=ni*16+l15, row within group s = lg*4+reg).
#define STAGE_WEIGHTS()                                                          \
    {                                                                            \
        const int4* w2b16 = (const int4*)w2b;                                    \
        _Pragma("unroll")                                                        \
        for (int q = 0; q < 8; ++q) {                                            \
            const int i = threadIdx.x + q * 256;                                 \
            const int n_ = i >> 5, s_ = i & 31;                                  \
            lds[n_ * 32 + (s_ ^ (n_ & 7))] = w2b16[i];                           \
        }                                                                        \
        lds[2048 + (threadIdx.x ^ ((threadIdx.x >> 3) & 3))] =                   \
            ((const int4*)w1p)[threadIdx.x];                                     \
    }

#define MLP_SOFTMAX_CORE()                                                       \
    float rr[4], gg[4], uu[4];                                                   \
    _Pragma("unroll")                                                            \
    for (int s = 0; s < 4; ++s) {                                                \
        const int px = pwb + s * 16 + l15;                                       \
        rr[s] = ip[px]; gg[s] = ip[HW + px]; uu[s] = ip[2 * HW + px];            \
    }                                                                            \
    f32x4 acc[4][4];                                                             \
    _Pragma("unroll")                                                            \
    for (int s = 0; s < 4; ++s)                                                  \
        _Pragma("unroll")                                                        \
        for (int ni = 0; ni < 4; ++ni)                                           \
            acc[s][ni] = (f32x4){0.f, 0.f, 0.f, 0.f};                            \
    _Pragma("unroll")                                                            \
    for (int c = 0; c < 8; ++c) {                                                \
        bf16x8 a0, a1, a2, a3;                                                   \
        _Pragma("unroll")                                                        \
        for (int j = 0; j < 8; ++j) {                                            \
            const int hid = c * 32 + lg * 8 + j;                                 \
            const float4 wv = *(const float4*)&lds[2048 + (hid ^ lg)];           \
            float t0 = fmaf(rr[0], wv.x, fmaf(gg[0], wv.y, fmaf(uu[0], wv.z, wv.w))); \
            float t1 = fmaf(rr[1], wv.x, fmaf(gg[1], wv.y, fmaf(uu[1], wv.z, wv.w))); \
            float t2 = fmaf(rr[2], wv.x, fmaf(gg[2], wv.y, fmaf(uu[2], wv.z, wv.w))); \
            float t3 = fmaf(rr[3], wv.x, fmaf(gg[3], wv.y, fmaf(uu[3], wv.z, wv.w))); \
            a0[j] = f2bf(fmaxf(t0, 0.f));                                        \
            a1[j] = f2bf(fmaxf(t1, 0.f));                                        \
            a2[j] = f2bf(fmaxf(t2, 0.f));                                        \
            a3[j] = f2bf(fmaxf(t3, 0.f));                                        \
        }                                                                        \
        _Pragma("unroll")                                                        \
        for (int ni = 0; ni < 4; ++ni) {                                         \
            const int n = ni * 16 + l15;                                         \
            const bf16x8 bf = *(const bf16x8*)&lds[n * 32 + (((c * 4 + lg) ^ (n & 7)))]; \
            acc[0][ni] = __builtin_amdgcn_mfma_f32_16x16x32_bf16(a0, bf, acc[0][ni], 0, 0, 0); \
            acc[1][ni] = __builtin_amdgcn_mfma_f32_16x16x32_bf16(a1, bf, acc[1][ni], 0, 0, 0); \
            acc[2][ni] = __builtin_amdgcn_mfma_f32_16x16x32_bf16(a2, bf, acc[2][ni], 0, 0, 0); \
            acc[3][ni] = __builtin_amdgcn_mfma_f32_16x16x32_bf16(a3, bf, acc[3][ni], 0, 0, 0); \
        }                                                                        \
    }                                                                            \
    _Pragma("unroll")                                                            \
    for (int s = 0; s < 4; ++s) {                                                \
        _Pragma("unroll")                                                        \
        for (int reg = 0; reg < 4; ++reg) {                                      \
            float v0 = __expf(acc[s][0][reg]);                                   \
            float v1 = __expf(acc[s][1][reg]);                                   \
            float v2 = __expf(acc[s][2][reg]);                                   \
            float v3 = __expf(acc[s][3][reg]);                                   \
            float sm = (v0 + v1) + (v2 + v3);                                    \
            sm += __shfl_xor(sm, 1);                                             \
            sm += __shfl_xor(sm, 2);                                             \
            sm += __shfl_xor(sm, 4);                                             \
            sm += __shfl_xor(sm, 8);                                             \
            const float inv = 1.f / sm;                                          \
            acc[s][0][reg] = v0 * inv; acc[s][1][reg] = v1 * inv;                \
            acc[s][2][reg] = v2 * inv; acc[s][3][reg] = v3 * inv;                \
        }                                                                        \
    }

// Kernel A: MLP+softmax + fused den/num reduction + nontemporal m store (m not re-read on device).
__global__ __launch_bounds__(256) void colorcnn_mlp_softmax(
    const float* __restrict__ img, const float4* __restrict__ w1p,
    const ushort* __restrict__ w2b, float* __restrict__ m_out,
    float* __restrict__ den_ws, float* __restrict__ num_ws)
{
    __shared__ int4 lds[2304];
    __shared__ float sred[4][256];

    STAGE_WEIGHTS();
    __syncthreads();

    const int b    = blockIdx.y;
    const int pb   = blockIdx.x * 256;
    const int t    = threadIdx.x;
    const int w    = t >> 6;
    const int lane = t & 63;
    const int l15  = lane & 15;
    const int lg   = lane >> 4;
    const int pwb  = pb + w * 64;
    const float* ip = img + (size_t)b * 3 * HW;

    MLP_SOFTMAX_CORE();

    // ---- Fused den/num reduction (before global stores; barrier stays cheap) ----
    float red[16];
#pragma unroll
    for (int i = 0; i < 16; ++i) red[i] = 0.f;
#pragma unroll
    for (int s = 0; s < 4; ++s) {
        const int pxb = pwb + s * 16 + lg * 4;
        const f32x4 rC = *(const f32x4*)&ip[pxb];
        const f32x4 gC = *(const f32x4*)&ip[HW + pxb];
        const f32x4 uC = *(const f32x4*)&ip[2 * HW + pxb];
#pragma unroll
        for (int ni = 0; ni < 4; ++ni) {
#pragma unroll
            for (int reg = 0; reg < 4; ++reg) {
                const float mv = acc[s][ni][reg];
                red[ni]      += mv;
                red[4 + ni]   = fmaf(rC[reg], mv, red[4 + ni]);
                red[8 + ni]   = fmaf(gC[reg], mv, red[8 + ni]);
                red[12 + ni]  = fmaf(uC[reg], mv, red[12 + ni]);
            }
        }
    }
#pragma unroll
    for (int i = 0; i < 16; ++i) {
        red[i] += __shfl_xor(red[i], 16);
        red[i] += __shfl_xor(red[i], 32);
    }
    if (lg == 0) {
#pragma unroll
        for (int ni = 0; ni < 4; ++ni) {
            const int n = ni * 16 + l15;
            sred[w][n]       = red[ni];
            sred[w][64 + n]  = red[4 + ni];
            sred[w][128 + n] = red[8 + ni];
            sred[w][192 + n] = red[12 + ni];
        }
    }
    __syncthreads();
    {
        const int q = t >> 6, n = t & 63;
        const float v = sred[0][t] + sred[1][t] + sred[2][t] + sred[3][t];
        if (q == 0) atomicAdd(&den_ws[b * K + n], v);
        else        atomicAdd(&num_ws[(b * 3 + (q - 1)) * K + n], v);
    }

    // Store m LAST, nontemporal (never re-read on device).
    float* mo = m_out + (size_t)b * K * HW + pwb;
#pragma unroll
    for (int s = 0; s < 4; ++s)
#pragma unroll
        for (int ni = 0; ni < 4; ++ni) {
            const int n = ni * 16 + l15;
            __builtin_nontemporal_store(acc[s][ni],
                (f32x4*)&mo[(size_t)n * HW + s * 16 + lg * 4]);
        }
}

// Kernel C: recompute m (no 205 MB re-read), palette from ws, transformed via in-register
// k-reduction (shfl over the 16 n-columns). Tile-0 blocks write the palette output.
__global__ __launch_bounds__(256) void colorcnn_reconstruct(
    const float* __restrict__ img, const float4* __restrict__ w1p,
    const ushort* __restrict__ w2b, const float* __restrict__ den_ws,
    const float* __restrict__ num_ws, float* __restrict__ pal_out,
    float* __restrict__ t_out)
{
    __shared__ int4 lds[2304];
    __shared__ float pl[192];

    STAGE_WEIGHTS();

    const int b    = blockIdx.y;
    const int pb   = blockIdx.x * 256;
    const int t    = threadIdx.x;
    const int w    = t >> 6;
    const int lane = t & 63;
    const int l15  = lane & 15;
    const int lg   = lane >> 4;
    const int pwb  = pb + w * 64;
    const float* ip = img + (size_t)b * 3 * HW;

    if (t < 192) {
        const int c = t >> 6, k = t & 63;
        const float v = num_ws[(b * 3 + c) * K + k] / (den_ws[b * K + k] + 1e-8f);
        pl[t] = v;
        if (blockIdx.x == 0) pal_out[b * 3 * K + t] = v;
    }
    __syncthreads();   // covers lds staging + pl

    MLP_SOFTMAX_CORE();

    // palette values for this lane's 4 n-columns, 3 channels
    float pc[3][4];
#pragma unroll
    for (int c = 0; c < 3; ++c)
#pragma unroll
        for (int ni = 0; ni < 4; ++ni)
            pc[c][ni] = pl[c * K + ni * 16 + l15];

    float* to = t_out + (size_t)b * 3 * HW;
#pragma unroll
    for (int s = 0; s < 4; ++s) {
        float part[3][4];
#pragma unroll
        for (int c = 0; c < 3; ++c)
#pragma unroll
            for (int reg = 0; reg < 4; ++reg) {
                float v = acc[s][0][reg] * pc[c][0];
                v = fmaf(acc[s][1][reg], pc[c][1], v);
                v = fmaf(acc[s][2][reg], pc[c][2], v);
                v = fmaf(acc[s][3][reg], pc[c][3], v);
                part[c][reg] = v;
            }
#pragma unroll
        for (int c = 0; c < 3; ++c)
#pragma unroll
            for (int reg = 0; reg < 4; ++reg) {
                part[c][reg] += __shfl_xor(part[c][reg], 1);
                part[c][reg] += __shfl_xor(part[c][reg], 2);
                part[c][reg] += __shfl_xor(part[c][reg], 4);
                part[c][reg] += __shfl_xor(part[c][reg], 8);
            }
        if (l15 == 0) {
            const int px = pwb + s * 16 + lg * 4;
#pragma unroll
            for (int c = 0; c < 3; ++c) {
                f32x4 v = { part[c][0], part[c][1], part[c][2], part[c][3] };
                *(f32x4*)&to[(size_t)c * HW + px] = v;
            }
        }
    }
}

extern "C" void kernel_launch(void* const* d_in, const int* in_sizes, int n_in,
                              void* d_out, int out_size, void* d_ws, size_t ws_size,
                              hipStream_t stream) {
    const float* img = (const float*)d_in[0];
    const float* W1  = (const float*)d_in[1];
    const float* b1  = (const float*)d_in[2];
    const float* W2  = (const float*)d_in[3];

    float* out   = (float*)d_out;
    float* t_out = out + OUT_T_OFF;
    float* m_out = out + OUT_M_OFF;
    float* p_out = out + OUT_P_OFF;

    float*  wsf    = (float*)d_ws;
    float*  den_ws = wsf + WS_DEN;
    float*  num_ws = wsf + WS_NUM;
    float4* w1p    = (float4*)(wsf + WS_W1P);
    ushort* w2b    = (ushort*)(wsf + WS_W2B);

    colorcnn_prep<<<8, 256, 0, stream>>>(W1, b1, W2, wsf, w1p, w2b);
    colorcnn_mlp_softmax<<<dim3(HW / 256, BATCH), 256, 0, stream>>>(img, w1p, w2b, m_out, den_ws, num_ws);
    colorcnn_reconstruct<<<dim3(HW / 256, BATCH), 256, 0, stream>>>(img, w1p, w2b, den_ws, num_ws, p_out, t_out);
}

// Round 9
// 134.771 us; speedup vs baseline: 1.2206x; 1.2206x over previous
//
#include <hip/hip_runtime.h>
#include <hip/hip_bf16.h>

#define BATCH 16
#define HW 50176          // 224*224
#define HID 256
#define K 64

// output layout (floats): transformed [0, 2408448) | m [2408448, 53788672) | palette [53788672, +3072)
#define OUT_T_OFF 0
#define OUT_M_OFF 2408448
#define OUT_P_OFF 53788672

// workspace layout (floats): den [0,1024) | num [1024,4096) | w1p float4 [4096,5120) | w2b bf16 @ float-offset 5120 (32KB)
#define WS_DEN 0
#define WS_NUM 1024
#define WS_W1P 4096
#define WS_W2B 5120

typedef short bf16x8 __attribute__((ext_vector_type(8)));
typedef float f32x4  __attribute__((ext_vector_type(4)));

static __device__ __forceinline__ short f2bf(float x) {
    union { __hip_bfloat16 h; short s; } u;
    u.h = __float2bfloat16(x);
    return u.s;
}

// Prep (8 blocks): block 0 zeroes den/num and packs W1+b1; all blocks convert W2 slice to bf16.
__global__ __launch_bounds__(256) void colorcnn_prep(
    const float* __restrict__ W1, const float* __restrict__ b1,
    const float* __restrict__ W2, float* __restrict__ wsf,
    float4* __restrict__ w1p, ushort* __restrict__ w2b)
{
    const int t = threadIdx.x;
    if (blockIdx.x == 0) {
#pragma unroll
        for (int q = 0; q < 16; ++q) wsf[q * 256 + t] = 0.f;   // den[1024] + num[3072]
        w1p[t] = make_float4(W1[3 * t], W1[3 * t + 1], W1[3 * t + 2], b1[t]);
    }
#pragma unroll
    for (int q = 0; q < 8; ++q) {
        const int i = (blockIdx.x * 8 + q) * 256 + t;
        w2b[i] = (ushort)f2bf(W2[i]);
    }
}

// Kernel A: per-pixel MLP via MFMA + softmax (no max-subtract; logits bounded) + fused den/num
// reduction + m store last. Block = 256 px; 4 waves x 64 px each.  (v7 structure, unchanged)
__global__ __launch_bounds__(256) void colorcnn_mlp_softmax(
    const float* __restrict__ img, const float4* __restrict__ w1p,
    const ushort* __restrict__ w2b, float* __restrict__ m_out,
    float* __restrict__ den_ws, float* __restrict__ num_ws)
{
    __shared__ int4 lds[2304];       // [0,2048): w2b swizzled; [2048,2304): w1p swizzled
    __shared__ float sred[4][256];   // per-wave den/num partials

    const int t = threadIdx.x;
    const int4* w2b16 = (const int4*)w2b;
#pragma unroll
    for (int q = 0; q < 8; ++q) {
        const int i = t + q * 256;
        const int n = i >> 5, s = i & 31;
        lds[n * 32 + (s ^ (n & 7))] = w2b16[i];
    }
    lds[2048 + (t ^ ((t >> 3) & 3))] = ((const int4*)w1p)[t];
    __syncthreads();

    const int b    = blockIdx.y;
    const int pb   = blockIdx.x * 256;
    const int w    = t >> 6;
    const int lane = t & 63;
    const int l15  = lane & 15;
    const int lg   = lane >> 4;
    const int pwb  = pb + w * 64;

    const float* ip = img + (size_t)b * 3 * HW;

    float rr[4], gg[4], uu[4];
#pragma unroll
    for (int s = 0; s < 4; ++s) {
        const int px = pwb + s * 16 + l15;
        rr[s] = ip[px]; gg[s] = ip[HW + px]; uu[s] = ip[2 * HW + px];
    }

    f32x4 acc[4][4];
#pragma unroll
    for (int s = 0; s < 4; ++s)
#pragma unroll
        for (int ni = 0; ni < 4; ++ni)
            acc[s][ni] = (f32x4){0.f, 0.f, 0.f, 0.f};

#pragma unroll
    for (int c = 0; c < 8; ++c) {
        bf16x8 a0, a1, a2, a3;
#pragma unroll
        for (int j = 0; j < 8; ++j) {
            const int hid = c * 32 + lg * 8 + j;
            const float4 wv = *(const float4*)&lds[2048 + (hid ^ lg)];
            float t0 = fmaf(rr[0], wv.x, fmaf(gg[0], wv.y, fmaf(uu[0], wv.z, wv.w)));
            float t1 = fmaf(rr[1], wv.x, fmaf(gg[1], wv.y, fmaf(uu[1], wv.z, wv.w)));
            float t2 = fmaf(rr[2], wv.x, fmaf(gg[2], wv.y, fmaf(uu[2], wv.z, wv.w)));
            float t3 = fmaf(rr[3], wv.x, fmaf(gg[3], wv.y, fmaf(uu[3], wv.z, wv.w)));
            a0[j] = f2bf(fmaxf(t0, 0.f));
            a1[j] = f2bf(fmaxf(t1, 0.f));
            a2[j] = f2bf(fmaxf(t2, 0.f));
            a3[j] = f2bf(fmaxf(t3, 0.f));
        }
#pragma unroll
        for (int ni = 0; ni < 4; ++ni) {
            const int n = ni * 16 + l15;
            const bf16x8 bf = *(const bf16x8*)&lds[n * 32 + (((c * 4 + lg) ^ (n & 7)))];
            acc[0][ni] = __builtin_amdgcn_mfma_f32_16x16x32_bf16(a0, bf, acc[0][ni], 0, 0, 0);
            acc[1][ni] = __builtin_amdgcn_mfma_f32_16x16x32_bf16(a1, bf, acc[1][ni], 0, 0, 0);
            acc[2][ni] = __builtin_amdgcn_mfma_f32_16x16x32_bf16(a2, bf, acc[2][ni], 0, 0, 0);
            acc[3][ni] = __builtin_amdgcn_mfma_f32_16x16x32_bf16(a3, bf, acc[3][ni], 0, 0, 0);
        }
    }

#pragma unroll
    for (int s = 0; s < 4; ++s) {
#pragma unroll
        for (int reg = 0; reg < 4; ++reg) {
            float v0 = __expf(acc[s][0][reg]);
            float v1 = __expf(acc[s][1][reg]);
            float v2 = __expf(acc[s][2][reg]);
            float v3 = __expf(acc[s][3][reg]);
            float sm = (v0 + v1) + (v2 + v3);
            sm += __shfl_xor(sm, 1);
            sm += __shfl_xor(sm, 2);
            sm += __shfl_xor(sm, 4);
            sm += __shfl_xor(sm, 8);
            const float inv = 1.f / sm;
            acc[s][0][reg] = v0 * inv; acc[s][1][reg] = v1 * inv;
            acc[s][2][reg] = v2 * inv; acc[s][3][reg] = v3 * inv;
        }
    }

    // ---- Fused den/num reduction (before global stores; barrier stays cheap) ----
    float red[16];
#pragma unroll
    for (int i = 0; i < 16; ++i) red[i] = 0.f;
#pragma unroll
    for (int s = 0; s < 4; ++s) {
        const int pxb = pwb + s * 16 + lg * 4;
        const f32x4 rC = *(const f32x4*)&ip[pxb];
        const f32x4 gC = *(const f32x4*)&ip[HW + pxb];
        const f32x4 uC = *(const f32x4*)&ip[2 * HW + pxb];
#pragma unroll
        for (int ni = 0; ni < 4; ++ni) {
#pragma unroll
            for (int reg = 0; reg < 4; ++reg) {
                const float mv = acc[s][ni][reg];
                red[ni]      += mv;
                red[4 + ni]   = fmaf(rC[reg], mv, red[4 + ni]);
                red[8 + ni]   = fmaf(gC[reg], mv, red[8 + ni]);
                red[12 + ni]  = fmaf(uC[reg], mv, red[12 + ni]);
            }
        }
    }
#pragma unroll
    for (int i = 0; i < 16; ++i) {
        red[i] += __shfl_xor(red[i], 16);
        red[i] += __shfl_xor(red[i], 32);
    }
    if (lg == 0) {
#pragma unroll
        for (int ni = 0; ni < 4; ++ni) {
            const int n = ni * 16 + l15;
            sred[w][n]       = red[ni];
            sred[w][64 + n]  = red[4 + ni];
            sred[w][128 + n] = red[8 + ni];
            sred[w][192 + n] = red[12 + ni];
        }
    }
    __syncthreads();
    {
        const int q = t >> 6, n = t & 63;
        const float v = sred[0][t] + sred[1][t] + sred[2][t] + sred[3][t];
        if (q == 0) atomicAdd(&den_ws[b * K + n], v);
        else        atomicAdd(&num_ws[(b * 3 + (q - 1)) * K + n], v);
    }

    // Store m LAST: per (s,ni) the 4 regs are 4 consecutive px -> dwordx4 (64B-aligned chunks).
    float* mo = m_out + (size_t)b * K * HW + pwb;
#pragma unroll
    for (int s = 0; s < 4; ++s)
#pragma unroll
        for (int ni = 0; ni < 4; ++ni) {
            const int n = ni * 16 + l15;
            *(f32x4*)&mo[(size_t)n * HW + s * 16 + lg * 4] = acc[s][ni];
        }
}

// Kernel C: palette (fused) + transformed = sum_k m * palette.
// 1 px/thread, 3136 blocks -> ~12 blocks/CU for max TLP; nontemporal dword m loads
// (m has no reuse; keep L2 clean); dword stores with 256B/inst contiguity.
__global__ __launch_bounds__(256) void colorcnn_reconstruct(
    const float* __restrict__ m, const float* __restrict__ den_ws,
    const float* __restrict__ num_ws, float* __restrict__ pal_out,
    float* __restrict__ t_out)
{
    __shared__ float pl[192];
    const int b    = blockIdx.y;
    const int tile = blockIdx.x;
    const int t    = threadIdx.x;

    if (t < 192) {
        const int c = t >> 6, k = t & 63;
        const float v = num_ws[(b * 3 + c) * K + k] / (den_ws[b * K + k] + 1e-8f);
        pl[t] = v;
        if (tile == 0) pal_out[b * 3 * K + t] = v;
    }
    __syncthreads();

    const int p = tile * 256 + t;
    const float* mp = m + (size_t)b * K * HW + p;
    float ar = 0.f, ag = 0.f, ab = 0.f;
#pragma unroll
    for (int k = 0; k < K; ++k) {
        const float mv = __builtin_nontemporal_load(&mp[(size_t)k * HW]);
        ar = fmaf(mv, pl[k],         ar);
        ag = fmaf(mv, pl[K + k],     ag);
        ab = fmaf(mv, pl[2 * K + k], ab);
    }
    float* to = t_out + (size_t)b * 3 * HW + p;
    to[0]      = ar;
    to[HW]     = ag;
    to[2 * HW] = ab;
}

extern "C" void kernel_launch(void* const* d_in, const int* in_sizes, int n_in,
                              void* d_out, int out_size, void* d_ws, size_t ws_size,
                              hipStream_t stream) {
    const float* img = (const float*)d_in[0];
    const float* W1  = (const float*)d_in[1];
    const float* b1  = (const float*)d_in[2];
    const float* W2  = (const float*)d_in[3];

    float* out   = (float*)d_out;
    float* t_out = out + OUT_T_OFF;
    float* m_out = out + OUT_M_OFF;
    float* p_out = out + OUT_P_OFF;

    float*  wsf    = (float*)d_ws;
    float*  den_ws = wsf + WS_DEN;
    float*  num_ws = wsf + WS_NUM;
    float4* w1p    = (float4*)(wsf + WS_W1P);
    ushort* w2b    = (ushort*)(wsf + WS_W2B);

    colorcnn_prep<<<8, 256, 0, stream>>>(W1, b1, W2, wsf, w1p, w2b);
    colorcnn_mlp_softmax<<<dim3(HW / 256, BATCH), 256, 0, stream>>>(img, w1p, w2b, m_out, den_ws, num_ws);
    colorcnn_reconstruct<<<dim3(HW / 256, BATCH), 256, 0, stream>>>(m_out, den_ws, num_ws, p_out, t_out);
}

// Round 10
// 124.986 us; speedup vs baseline: 1.3162x; 1.0783x over previous
//
#include <hip/hip_runtime.h>
#include <hip/hip_bf16.h>

#define BATCH 16
#define HW 50176          // 224*224
#define HID 256
#define K 64

// output layout (floats): transformed [0, 2408448) | m [2408448, 53788672) | palette [53788672, +3072)
#define OUT_T_OFF 0
#define OUT_M_OFF 2408448
#define OUT_P_OFF 53788672

// workspace layout (floats): den [0,1024) | num [1024,4096) | w1p float4 [4096,5120) | w2b bf16 @ float-offset 5120 (32KB)
#define WS_DEN 0
#define WS_NUM 1024
#define WS_W1P 4096
#define WS_W2B 5120

typedef short bf16x8 __attribute__((ext_vector_type(8)));
typedef float f32x4  __attribute__((ext_vector_type(4)));

static __device__ __forceinline__ short f2bf(float x) {
    union { __hip_bfloat16 h; short s; } u;
    u.h = __float2bfloat16(x);
    return u.s;
}

// Prep (8 blocks): block 0 zeroes den/num and packs W1+b1 (linear); all blocks convert W2 to bf16.
__global__ __launch_bounds__(256) void colorcnn_prep(
    const float* __restrict__ W1, const float* __restrict__ b1,
    const float* __restrict__ W2, float* __restrict__ wsf,
    float4* __restrict__ w1p, ushort* __restrict__ w2b)
{
    const int t = threadIdx.x;
    if (blockIdx.x == 0) {
#pragma unroll
        for (int q = 0; q < 16; ++q) wsf[q * 256 + t] = 0.f;   // den[1024] + num[3072]
        w1p[t] = make_float4(W1[3 * t], W1[3 * t + 1], W1[3 * t + 2], b1[t]);
    }
#pragma unroll
    for (int q = 0; q < 8; ++q) {
        const int i = (blockIdx.x * 8 + q) * 256 + t;
        w2b[i] = (ushort)f2bf(W2[i]);
    }
}

// Kernel A: MLP via MFMA + softmax + fused den/num reduction + m store last.
// 32 px/wave (acc[2][4] = 32 VGPR), __launch_bounds__(256,4) caps VGPR at 128 -> 4 blocks/CU.
// Block = 128 px; grid (HW/128, BATCH).
__global__ __launch_bounds__(256, 4) void colorcnn_mlp_softmax(
    const float* __restrict__ img, const float4* __restrict__ w1p,
    const ushort* __restrict__ w2b, float* __restrict__ m_out,
    float* __restrict__ den_ws, float* __restrict__ num_ws)
{
    __shared__ int4 lds[2304];       // [0,2048): w2b swizzled; [2048,2304): w1p LINEAR
    __shared__ float sred[4][256];   // per-wave den/num partials

    const int t = threadIdx.x;
    const int4* w2b16 = (const int4*)w2b;
#pragma unroll
    for (int q = 0; q < 8; ++q) {
        const int i = t + q * 256;
        const int n = i >> 5, s = i & 31;
        lds[n * 32 + (s ^ (n & 7))] = w2b16[i];
    }
    lds[2048 + t] = ((const int4*)w1p)[t];   // linear: reads become base+imm-offset
    __syncthreads();

    const int b    = blockIdx.y;
    const int pb   = blockIdx.x * 128;
    const int w    = t >> 6;
    const int lane = t & 63;
    const int l15  = lane & 15;
    const int lg   = lane >> 4;
    const int pwb  = pb + w * 32;
    const int x7   = l15 & 7;

    const float* ip = img + (size_t)b * 3 * HW;

    float rr[2], gg[2], uu[2];
#pragma unroll
    for (int s = 0; s < 2; ++s) {
        const int px = pwb + s * 16 + l15;
        rr[s] = ip[px]; gg[s] = ip[HW + px]; uu[s] = ip[2 * HW + px];
    }

    f32x4 acc[2][4];
#pragma unroll
    for (int s = 0; s < 2; ++s)
#pragma unroll
        for (int ni = 0; ni < 4; ++ni)
            acc[s][ni] = (f32x4){0.f, 0.f, 0.f, 0.f};

    // w1p base for this lane's hid group: entries are 16B; hid = c*32 + lg*8 + j
    const float4* w1l = (const float4*)&lds[2048 + lg * 8];

#pragma unroll
    for (int c = 0; c < 8; ++c) {
        union { bf16x8 v; unsigned int u[4]; } ua0, ua1;
#pragma unroll
        for (int p = 0; p < 4; ++p) {          // j = 2p, 2p+1
            const float4 wv0 = w1l[c * 32 + 2 * p];
            const float4 wv1 = w1l[c * 32 + 2 * p + 1];
            const float e0 = fmaxf(fmaf(rr[0], wv0.x, fmaf(gg[0], wv0.y, fmaf(uu[0], wv0.z, wv0.w))), 0.f);
            const float o0 = fmaxf(fmaf(rr[0], wv1.x, fmaf(gg[0], wv1.y, fmaf(uu[0], wv1.z, wv1.w))), 0.f);
            const float e1 = fmaxf(fmaf(rr[1], wv0.x, fmaf(gg[1], wv0.y, fmaf(uu[1], wv0.z, wv0.w))), 0.f);
            const float o1 = fmaxf(fmaf(rr[1], wv1.x, fmaf(gg[1], wv1.y, fmaf(uu[1], wv1.z, wv1.w))), 0.f);
            __hip_bfloat162 c0 = __float22bfloat162_rn(float2{e0, o0});   // packed cvt
            __hip_bfloat162 c1 = __float22bfloat162_rn(float2{e1, o1});
            ua0.u[p] = *(unsigned int*)&c0;
            ua1.u[p] = *(unsigned int*)&c1;
        }
        const int sw = (c * 4 + lg) ^ x7;
#pragma unroll
        for (int ni = 0; ni < 4; ++ni) {
            const bf16x8 bf = *(const bf16x8*)&lds[(ni * 16 + l15) * 32 + sw];
            acc[0][ni] = __builtin_amdgcn_mfma_f32_16x16x32_bf16(ua0.v, bf, acc[0][ni], 0, 0, 0);
            acc[1][ni] = __builtin_amdgcn_mfma_f32_16x16x32_bf16(ua1.v, bf, acc[1][ni], 0, 0, 0);
        }
    }

    // Softmax over n=64 per pixel (no max-subtract; logits bounded, fp32 exp safe).
#pragma unroll
    for (int s = 0; s < 2; ++s) {
#pragma unroll
        for (int reg = 0; reg < 4; ++reg) {
            const float v0 = __expf(acc[s][0][reg]);
            const float v1 = __expf(acc[s][1][reg]);
            const float v2 = __expf(acc[s][2][reg]);
            const float v3 = __expf(acc[s][3][reg]);
            float sm = (v0 + v1) + (v2 + v3);
            sm += __shfl_xor(sm, 1);
            sm += __shfl_xor(sm, 2);
            sm += __shfl_xor(sm, 4);
            sm += __shfl_xor(sm, 8);
            const float inv = __builtin_amdgcn_rcpf(sm);   // 1 op vs ~10-op exact div
            acc[s][0][reg] = v0 * inv; acc[s][1][reg] = v1 * inv;
            acc[s][2][reg] = v2 * inv; acc[s][3][reg] = v3 * inv;
        }
    }

    // ---- Fused den/num reduction (before global stores; barrier stays cheap) ----
    float red[16];   // [q*4+ni], q: 0=den 1=numR 2=numG 3=numB
#pragma unroll
    for (int i = 0; i < 16; ++i) red[i] = 0.f;
#pragma unroll
    for (int s = 0; s < 2; ++s) {
        const int pxb = pwb + s * 16 + lg * 4;
        const f32x4 rC = *(const f32x4*)&ip[pxb];
        const f32x4 gC = *(const f32x4*)&ip[HW + pxb];
        const f32x4 uC = *(const f32x4*)&ip[2 * HW + pxb];
#pragma unroll
        for (int ni = 0; ni < 4; ++ni) {
#pragma unroll
            for (int reg = 0; reg < 4; ++reg) {
                const float mv = acc[s][ni][reg];
                red[ni]      += mv;
                red[4 + ni]   = fmaf(rC[reg], mv, red[4 + ni]);
                red[8 + ni]   = fmaf(gC[reg], mv, red[8 + ni]);
                red[12 + ni]  = fmaf(uC[reg], mv, red[12 + ni]);
            }
        }
    }
#pragma unroll
    for (int i = 0; i < 16; ++i) {
        red[i] += __shfl_xor(red[i], 16);
        red[i] += __shfl_xor(red[i], 32);
    }
    if (lg == 0) {
#pragma unroll
        for (int ni = 0; ni < 4; ++ni) {
            const int n = ni * 16 + l15;
            sred[w][n]       = red[ni];
            sred[w][64 + n]  = red[4 + ni];
            sred[w][128 + n] = red[8 + ni];
            sred[w][192 + n] = red[12 + ni];
        }
    }
    __syncthreads();
    {
        const int q = t >> 6, n = t & 63;
        const float v = sred[0][t] + sred[1][t] + sred[2][t] + sred[3][t];
        if (q == 0) atomicAdd(&den_ws[b * K + n], v);
        else        atomicAdd(&num_ws[(b * 3 + (q - 1)) * K + n], v);
    }

    // Store m LAST: per (s,ni) the 4 regs are 4 consecutive px -> dwordx4.
    float* mo = m_out + (size_t)b * K * HW + pwb;
#pragma unroll
    for (int s = 0; s < 2; ++s)
#pragma unroll
        for (int ni = 0; ni < 4; ++ni) {
            const int n = ni * 16 + l15;
            *(f32x4*)&mo[(size_t)n * HW + s * 16 + lg * 4] = acc[s][ni];
        }
}

// Kernel C: palette (fused) + transformed = sum_k m * palette. 4 px/thread, f32x4.
// (v7 version verbatim — best measured config.)
__global__ __launch_bounds__(256) void colorcnn_reconstruct(
    const float* __restrict__ m, const float* __restrict__ den_ws,
    const float* __restrict__ num_ws, float* __restrict__ pal_out,
    float* __restrict__ t_out)
{
    __shared__ float pl[192];
    const int b    = blockIdx.x / 49;
    const int tile = blockIdx.x % 49;
    const int t    = threadIdx.x;

    if (t < 192) {
        const int c = t >> 6, k = t & 63;
        const float v = num_ws[(b * 3 + c) * K + k] / (den_ws[b * K + k] + 1e-8f);
        pl[t] = v;
        if (tile == 0) pal_out[b * 3 * K + t] = v;
    }
    __syncthreads();

    const int p = tile * 1024 + t * 4;
    const float* mp = m + (size_t)b * K * HW + p;
    f32x4 ar = {0.f, 0.f, 0.f, 0.f}, ag = ar, ab = ar;
#pragma unroll
    for (int k = 0; k < K; ++k) {
        const f32x4 mv = *(const f32x4*)&mp[(size_t)k * HW];
        const float pr = pl[k], pg = pl[K + k], pu = pl[2 * K + k];
#pragma unroll
        for (int j = 0; j < 4; ++j) {
            ar[j] = fmaf(mv[j], pr, ar[j]);
            ag[j] = fmaf(mv[j], pg, ag[j]);
            ab[j] = fmaf(mv[j], pu, ab[j]);
        }
    }
    float* to = t_out + (size_t)b * 3 * HW + p;
    *(f32x4*)&to[0]      = ar;
    *(f32x4*)&to[HW]     = ag;
    *(f32x4*)&to[2 * HW] = ab;
}

extern "C" void kernel_launch(void* const* d_in, const int* in_sizes, int n_in,
                              void* d_out, int out_size, void* d_ws, size_t ws_size,
                              hipStream_t stream) {
    const float* img = (const float*)d_in[0];
    const float* W1  = (const float*)d_in[1];
    const float* b1  = (const float*)d_in[2];
    const float* W2  = (const float*)d_in[3];

    float* out   = (float*)d_out;
    float* t_out = out + OUT_T_OFF;
    float* m_out = out + OUT_M_OFF;
    float* p_out = out + OUT_P_OFF;

    float*  wsf    = (float*)d_ws;
    float*  den_ws = wsf + WS_DEN;
    float*  num_ws = wsf + WS_NUM;
    float4* w1p    = (float4*)(wsf + WS_W1P);
    ushort* w2b    = (ushort*)(wsf + WS_W2B);

    colorcnn_prep<<<8, 256, 0, stream>>>(W1, b1, W2, wsf, w1p, w2b);
    colorcnn_mlp_softmax<<<dim3(HW / 128, BATCH), 256, 0, stream>>>(img, w1p, w2b, m_out, den_ws, num_ws);
    colorcnn_reconstruct<<<BATCH * 49, 256, 0, stream>>>(m_out, den_ws, num_ws, p_out, t_out);
}